// Round 7
// baseline (186.075 us; speedup 1.0000x reference)
//
#include <hip/hip_runtime.h>
#include <stdint.h>

// ---------------------------------------------------------------------------
// BNNLinear: out = BatchNorm( sign(x) @ sign(W)^T )
//   x: [M, K] f32, W: [N, K] f32, gamma/beta: [N] f32  ->  out: [M, N] f32
//
// Round 7 (on round 6: i8 MFMA, XOR swizzle -> 0 conflicts, i16 raw C,
// 4 blocks/CU):
//   GEMM K-loop restructured to double-buffered LDS, BK=64:
//     prefetch -> loop { barrier; ds_read buf[p]; DMA next -> buf[1-p];
//                        mfma; p^=1 }
//   One barrier/iter; its implicit vmcnt(0) drain now waits on a DMA issued
//   a FULL iteration earlier (latency hidden) instead of one issued
//   immediately before (R6: full DMA latency exposed 16x).
//   LDS = 2x(8+8) KB = 32 KB -> keeps 4 blocks/CU (m132's occupancy trap
//   avoided). Swizzle adapted to 64B rows: chunk ^ (row&3).
// ---------------------------------------------------------------------------

typedef int int32x4 __attribute__((ext_vector_type(4)));

#define BM 128
#define BN 128
#define BKI 64   // i8 k-bytes per tile (double-buffered)
#define EPS_BN 1e-5f

__device__ __forceinline__ void load16_lds(const void* g, void* l) {
  // 16B per lane, LDS dest = wave-uniform base + lane*16 (linear, no scatter)
  __builtin_amdgcn_global_load_lds(
      (const __attribute__((address_space(1))) void*)g,
      (__attribute__((address_space(3))) void*)l,
      16, 0, 0);
}

__device__ __forceinline__ char sgn(float v) {
  return v > 0.f ? (char)1 : (v < 0.f ? (char)-1 : (char)0);
}

// ---- 1) binarize f32 -> i8 sign (both tensors) + zero stats ---------------
__global__ void binarize_kernel(const float* __restrict__ x,
                                const float* __restrict__ w,
                                char* __restrict__ Ab, char* __restrict__ Bb,
                                float* __restrict__ stats,  // colSum|colSq
                                int nx4, int ntot4, int n2) {
  int idx = blockIdx.x * blockDim.x + threadIdx.x;
  if (idx < n2) stats[idx] = 0.f;
  if (idx >= ntot4) return;
  const float4* src;
  char* dst;
  int i;
  if (idx < nx4) {
    src = reinterpret_cast<const float4*>(x); dst = Ab; i = idx;
  } else {
    src = reinterpret_cast<const float4*>(w); dst = Bb; i = idx - nx4;
  }
  float4 v = src[i];
  char4 o;
  o.x = sgn(v.x); o.y = sgn(v.y); o.z = sgn(v.z); o.w = sgn(v.w);
  reinterpret_cast<char4*>(dst)[i] = o;
}

// ---- 2) GEMM: C[i][j] = sum_k A[i][k]*Bt[j][k] (i8 -> i32 exact) ----------
// LDS swizzle (64B rows, 4x16B chunks): row r chunk slot c holds global
// chunk (c ^ (r&3)); XOR applied on the GLOBAL source address so the DMA
// dest stays linear. Readers apply the same XOR. Bank group =
// (r&1)*4 + chunk: 8 groups x 2 lanes per quarter-wave (R5-measured-free
// density).
__global__ __launch_bounds__(256, 4) void gemm_i8_kernel(
    const char* __restrict__ A,    // [M][K] i8
    const char* __restrict__ Bt,   // [N][K] i8
    short* __restrict__ Craw,      // [M][N] i16 (exact: |C| <= K)
    float* __restrict__ colSum,    // [N] (pre-zeroed)
    float* __restrict__ colSq,     // [N] (pre-zeroed)
    int M, int N, int K) {
  // double-buffered tiles: [buf][A 8KB | B 8KB]
  __shared__ __align__(16) char sT[2][BM * BKI + BN * BKI];  // 32 KiB

  const int tid  = threadIdx.x;
  const int wave = tid >> 6;
  const int lane = tid & 63;

  // consecutive block-ids share the same B panel (L2 locality)
  const int nby = M / BM;
  const int rowBlock = (blockIdx.x % nby) * BM;
  const int colBlock = (blockIdx.x / nby) * BN;

  // staging: per wave 32 rows A + 32 rows B; one call = 64 lanes x 16B
  // = 16 rows x 64B. 2 calls each.
  const int laneRow = lane >> 2;                 // 0..15 (== row & 15)
  const int c       = lane & 3;                  // chunk slot 0..3
  const int swz     = ((c ^ laneRow) & 3) * 16;  // global k-byte offset

  const char* Ag = A  + (size_t)(rowBlock + wave * 32 + laneRow) * K + swz;
  const char* Bg = Bt + (size_t)(colBlock + wave * 32 + laneRow) * K + swz;
  const int sAoff = (wave * 32) * BKI;            // within A region
  const int sBoff = BM * BKI + (wave * 32) * BKI; // within B region

  const int f    = lane & 15;  // m (A) / n (B) index
  const int quad = lane >> 4;  // k-chunk selector (16B each, 4 per row)
  const int wr = (wave >> 1) * 64;
  const int wc = (wave & 1) * 64;
  const int rchunk = quad ^ (f & 3);  // swizzled read chunk

  int32x4 acc[4][4] = {};

  // prefetch k0 = 0 into buffer 0
#pragma unroll
  for (int i = 0; i < 2; ++i) {
    load16_lds(Ag + (size_t)(i * 16) * K, &sT[0][sAoff + i * 16 * BKI]);
    load16_lds(Bg + (size_t)(i * 16) * K, &sT[0][sBoff + i * 16 * BKI]);
  }

  int p = 0;
  for (int k0 = 0; k0 < K; k0 += BKI) {
    __syncthreads();  // drains DMA issued one full iteration ago + ds_reads

    // read this iter's fragments from buf p
    int32x4 af[4], bfr[4];
#pragma unroll
    for (int mi = 0; mi < 4; ++mi)
      af[mi] = *reinterpret_cast<const int32x4*>(
          &sT[p][(wr + mi * 16 + f) * BKI + rchunk * 16]);
#pragma unroll
    for (int ni = 0; ni < 4; ++ni)
      bfr[ni] = *reinterpret_cast<const int32x4*>(
          &sT[p][BM * BKI + (wc + ni * 16 + f) * BKI + rchunk * 16]);

    // issue DMA for next tile into the other buffer (hidden under mfma)
    const int kn = k0 + BKI;
    if (kn < K) {
#pragma unroll
      for (int i = 0; i < 2; ++i) {
        load16_lds(Ag + kn + (size_t)(i * 16) * K,
                   &sT[p ^ 1][sAoff + i * 16 * BKI]);
        load16_lds(Bg + kn + (size_t)(i * 16) * K,
                   &sT[p ^ 1][sBoff + i * 16 * BKI]);
      }
    }

#pragma unroll
    for (int mi = 0; mi < 4; ++mi)
#pragma unroll
      for (int ni = 0; ni < 4; ++ni)
        acc[mi][ni] = __builtin_amdgcn_mfma_i32_16x16x64_i8(
            af[mi], bfr[ni], acc[mi][ni], 0, 0, 0);

    p ^= 1;
  }

  // epilogue: C/D layout col = lane&15, row = quad*4 + reg (verified).
  // Store raw C as int16 (exact); per-column sum/sumsq atomics (exact).
#pragma unroll
  for (int ni = 0; ni < 4; ++ni) {
    const int col = colBlock + wc + ni * 16 + f;
    float s = 0.f, sq = 0.f;
#pragma unroll
    for (int mi = 0; mi < 4; ++mi) {
      short* Cp = Craw + (size_t)(rowBlock + wr + mi * 16 + quad * 4) * N + col;
#pragma unroll
      for (int r = 0; r < 4; ++r) {
        const int v = acc[mi][ni][r];
        Cp[(size_t)r * N] = (short)v;
        const float fv = (float)v;
        s += fv;
        sq += fv * fv;
      }
    }
    s  += __shfl_xor(s, 16);  s  += __shfl_xor(s, 32);
    sq += __shfl_xor(sq, 16); sq += __shfl_xor(sq, 32);
    if (quad == 0) {
      atomicAdd(&colSum[col], s);
      atomicAdd(&colSq[col], sq);
    }
  }
}

// ---- 3) finalize + normalize: C = raw*scale + shift (2 rows/thread) -------
__global__ void norm_kernel(const short* __restrict__ Craw,
                            float* __restrict__ C,
                            const float* __restrict__ colSum,
                            const float* __restrict__ colSq,
                            const float* __restrict__ gamma,
                            const float* __restrict__ beta,
                            int ncol4mask, int ncol4shift, int halfRows,
                            float invM) {
  const int idx = blockIdx.x * blockDim.x + threadIdx.x;
  const int c4  = idx & ncol4mask;  // N/4 is a power of two
  const int row = idx >> ncol4shift;
  const int col = c4 * 4;
  const int ncol4 = ncol4mask + 1;

  const float4 sm = *reinterpret_cast<const float4*>(&colSum[col]);
  const float4 sv = *reinterpret_cast<const float4*>(&colSq[col]);
  const float4 g  = *reinterpret_cast<const float4*>(&gamma[col]);
  const float4 b  = *reinterpret_cast<const float4*>(&beta[col]);

  float4 sc, sh;
  {
    float m, vv;
    m = sm.x * invM; vv = sv.x * invM - m * m;
    sc.x = g.x * rsqrtf(vv + EPS_BN); sh.x = b.x - m * sc.x;
    m = sm.y * invM; vv = sv.y * invM - m * m;
    sc.y = g.y * rsqrtf(vv + EPS_BN); sh.y = b.y - m * sc.y;
    m = sm.z * invM; vv = sv.z * invM - m * m;
    sc.z = g.z * rsqrtf(vv + EPS_BN); sh.z = b.z - m * sc.z;
    m = sm.w * invM; vv = sv.w * invM - m * m;
    sc.w = g.w * rsqrtf(vv + EPS_BN); sh.w = b.w - m * sc.w;
  }

#pragma unroll
  for (int h = 0; h < 2; ++h) {
    const size_t e = (size_t)(row + h * halfRows) * ncol4 + c4;
    const short4 rv = reinterpret_cast<const short4*>(Craw)[e];
    float4 o;
    o.x = (float)rv.x * sc.x + sh.x;
    o.y = (float)rv.y * sc.y + sh.y;
    o.z = (float)rv.z * sc.z + sh.z;
    o.w = (float)rv.w * sc.w + sh.w;
    reinterpret_cast<float4*>(C)[e] = o;
  }
}

// ---------------------------------------------------------------------------
extern "C" void kernel_launch(void* const* d_in, const int* in_sizes, int n_in,
                              void* d_out, int out_size, void* d_ws,
                              size_t ws_size, hipStream_t stream) {
  const float* x     = (const float*)d_in[0];
  const float* w     = (const float*)d_in[1];
  const float* gamma = (const float*)d_in[2];
  const float* beta  = (const float*)d_in[3];
  float* C = (float*)d_out;

  const int N = in_sizes[2];      // OUT
  const int K = in_sizes[1] / N;  // IN
  const int M = in_sizes[0] / K;  // batch

  // workspace: [A i8 M*K][B i8 N*K][Craw i16 M*N][colSum N][colSq N]
  char* ws = (char*)d_ws;
  char* Abin = ws;
  char* Bbin = ws + (size_t)M * K;
  short* Craw = (short*)(ws + (size_t)M * K + (size_t)N * K);
  float* stats = (float*)((char*)Craw + (size_t)M * N * sizeof(short));
  float* colSum = stats;
  float* colSq  = stats + N;

  {
    int nx4 = (M * K) / 4;
    int ntot4 = (M * K + N * K) / 4;
    binarize_kernel<<<(ntot4 + 255) / 256, 256, 0, stream>>>(
        x, w, Abin, Bbin, stats, nx4, ntot4, 2 * N);
  }

  const int nTiles = (M / BM) * (N / BN);  // 1024 = 256 CUs x 4 blocks
  gemm_i8_kernel<<<nTiles, 256, 0, stream>>>(Abin, Bbin, Craw, colSum, colSq,
                                             M, N, K);

  {
    int ncol4 = N / 4;  // power of two (512)
    int shift = 0;
    while ((1 << shift) < ncol4) ++shift;
    int total = (M / 2) * ncol4;  // 2 rows per thread
    norm_kernel<<<(total + 255) / 256, 256, 0, stream>>>(
        Craw, C, colSum, colSq, gamma, beta, ncol4 - 1, shift, M / 2,
        1.0f / (float)M);
  }
}